// Round 3
// baseline (917.210 us; speedup 1.0000x reference)
//
#include <hip/hip_runtime.h>

// Problem constants (fixed by setup_inputs)
#define NT   32768      // B*T tokens
#define NV   32         // V
#define DI   64         // I == H
#define VI   2048       // V*I

typedef __attribute__((ext_vector_type(8)))  short short8;    // 8 bf16 (4 VGPRs)
typedef __attribute__((ext_vector_type(16))) float floatx16;  // MFMA 32x32 acc

#define MFMA32(a,b,c) __builtin_amdgcn_mfma_f32_32x32x16_bf16(a, b, c, 0, 0, 0)

// ---- workspace layout (bytes) ----
#define WS_S      0                  // fp32 [NT][64]  (skip|elu(h1))      8,388,608
#define WS_WBUF   8388608            // fp32 [NT][32]  softmax weights     4,194,304
#define WS_WCOMBT 12582912           // bf16 frag-order A for k1             262,144
#define WS_WAV    12845056           // bf16 frag-order [32][15360]          983,040
#define WS_WC2    13828096           // fp32 [32][64]  folded wg W2@Wg         8,192
#define WS_BC2    13836288           // fp32 [64]                               256

static __device__ __forceinline__ unsigned short f2bf(float f) {
    union { float f; unsigned u; } v; v.f = f;
    unsigned r = v.u + 0x7FFFu + ((v.u >> 16) & 1u);   // RNE
    return (unsigned short)(r >> 16);
}
static __device__ __forceinline__ unsigned pk2bf(float lo, float hi) {
    return (unsigned)f2bf(lo) | ((unsigned)f2bf(hi) << 16);
}
static __device__ __forceinline__ float elu1(float v) {
    return (v > 0.f) ? v : (__expf(v) - 1.f);
}
static __device__ __forceinline__ float bflo(unsigned v) {
    union { unsigned u; float f; } t; t.u = v << 16; return t.f;
}
static __device__ __forceinline__ float bfhi(unsigned v) {
    union { unsigned u; float f; } t; t.u = v & 0xFFFF0000u; return t.f;
}

// ============================================================================
// K0: weight prep into FRAG-ORDER layouts.
//  WcombT_f: [c8 8][m 2][ks 16][s 2][l 32][8sh]; element = [Ws|W1] row k, col mr
//            k = 256*c8+16*ks+8*s+e ; mr = 32*m+l  (mr<32 -> Ws, else W1)
//  wAv_f[v]: [t6 6][ks 5][s 2][l 32][8sh]; kk = 16*ks+8*s+e (kk==64 bias, >64 zero)
//            t6 0..1: W1^T rows mr=32*t6+l ; t6 2..5: Wc^T rows n=32*(t6-2)+l
//            where Wc = v_W2 @ v_Wg (FOLDED), bias bc = v_b2@v_Wg + v_bg
//  Wc2 = wg_W2 @ wg_Wg (fp32), bc2 = wg_b2 @ wg_Wg + wg_bg (FOLDED)
// ============================================================================
__global__ void k0_prep(const float* __restrict__ wg_W1, const float* __restrict__ wg_Ws,
                        const float* __restrict__ wg_W2, const float* __restrict__ wg_b2,
                        const float* __restrict__ wg_Wg, const float* __restrict__ wg_bg,
                        const float* __restrict__ v_W1, const float* __restrict__ v_b1,
                        const float* __restrict__ v_W2, const float* __restrict__ v_b2,
                        const float* __restrict__ v_Wg, const float* __restrict__ v_bg,
                        unsigned short* __restrict__ WcombT, unsigned short* __restrict__ wAv,
                        float* __restrict__ Wc2, float* __restrict__ bc2) {
    int tid = blockIdx.x * blockDim.x + threadIdx.x;
    int np  = gridDim.x * blockDim.x;
    // A: WcombT frag-order
    for (int f = tid; f < 131072; f += np) {
        int e = f & 7, l = (f >> 3) & 31, s = (f >> 8) & 1;
        int ks = (f >> 9) & 15, m = (f >> 13) & 1, c8 = f >> 14;
        int k = c8 * 256 + ks * 16 + s * 8 + e;
        int mr = m * 32 + l;
        float val = (mr < 32) ? wg_Ws[k * 32 + mr] : wg_W1[k * 32 + (mr - 32)];
        WcombT[f] = f2bf(val);
    }
    // B: wAv W1 region (t6 = mr>>5), mr fastest for coalescing
    for (int i = tid; i < 32 * 80 * 64; i += np) {
        int mr = i & 63;
        int rest = i >> 6;
        int kk = rest % 80;
        int v  = rest / 80;
        float val = 0.f;
        if (kk < 64)       val = v_W1[(v * 64 + kk) * 64 + mr];
        else if (kk == 64) val = v_b1[v * 64 + mr];
        int t6 = mr >> 5, l = mr & 31, ks = kk >> 4, s = (kk >> 3) & 1, e = kk & 7;
        wAv[v * 15360 + ((t6 * 5 + ks) * 2 + s) * 256 + l * 8 + e] = f2bf(val);
    }
    // C: wAv Wc region (fold W2@Wg), n fastest for coalescing
    for (int i = tid; i < 32 * 80 * 128; i += np) {
        int n = i & 127;
        int rest = i >> 7;
        int kk = rest % 80;
        int v  = rest / 80;
        float acc = 0.f;
        if (kk < 64) {
            #pragma unroll 8
            for (int k2 = 0; k2 < 64; ++k2)
                acc += v_W2[(v * 64 + kk) * 64 + k2] * v_Wg[(v * 64 + k2) * 128 + n];
        } else if (kk == 64) {
            #pragma unroll 8
            for (int k2 = 0; k2 < 64; ++k2)
                acc += v_b2[v * 64 + k2] * v_Wg[(v * 64 + k2) * 128 + n];
            acc += v_bg[v * 128 + n];
        }
        int t6 = 2 + (n >> 5), l = n & 31, ks = kk >> 4, s = (kk >> 3) & 1, e = kk & 7;
        wAv[v * 15360 + ((t6 * 5 + ks) * 2 + s) * 256 + l * 8 + e] = f2bf(acc);
    }
    // D: Wc2 / bc2
    for (int i = tid; i < 32 * 64 + 64; i += np) {
        if (i < 2048) {
            int j = i >> 6, n = i & 63;
            float acc = 0.f;
            #pragma unroll 8
            for (int k = 0; k < 32; ++k) acc += wg_W2[j * 32 + k] * wg_Wg[k * 64 + n];
            Wc2[i] = acc;
        } else {
            int n = i - 2048;
            float acc = 0.f;
            #pragma unroll 8
            for (int k = 0; k < 32; ++k) acc += wg_b2[k] * wg_Wg[k * 64 + n];
            bc2[n] = acc + wg_bg[n];
        }
    }
}

// ============================================================================
// K1: S = [skip | elu(h1)], M=32768 K=2048 N=64.  Block = 64 tokens, 4 waves
// = (m outdim-half, th token-half). Contiguous global x reads (64B granule),
// bf16 frag-order LDS tile, double-buffered with register prefetch.
// A-frags: coalesced 1KB/wave loads from frag-order WcombT (L2-hot).
// ============================================================================
#define K1_BUF 33792      // 64 blks * 528 B
__launch_bounds__(256, 2)
__global__ void k1_wgemm(const float* __restrict__ x, const unsigned short* __restrict__ WcombT,
                         const float* __restrict__ wg_bs, const float* __restrict__ wg_b1,
                         float* __restrict__ S) {
    __shared__ __align__(16) unsigned char lds[2 * K1_BUF];
    int tid  = threadIdx.x;
    int wv   = tid >> 6, lane = tid & 63;
    int l31  = lane & 31, s = lane >> 5;
    int m    = wv & 1, th = wv >> 1;
    long tok0 = (long)blockIdx.x * 64;

    int r  = tid >> 2;          // staging row 0..63
    int c4 = tid & 3;           // 4 threads per row
    const float* xrow = x + (tok0 + r) * VI + c4 * 4;

    float4 pf[16];
    // ---- prologue: load + stage chunk 0 ----
    #pragma unroll
    for (int j = 0; j < 16; ++j) pf[j] = *(const float4*)(xrow + j * 16);
    {
        unsigned char* dst = lds;
        #pragma unroll
        for (int j = 0; j < 16; ++j) {
            int mm = c4 + 4 * j;
            int ks = mm >> 2, ss = (mm >> 1) & 1, e4 = mm & 1;
            int blk = ((r >> 5) * 16 + ks) * 2 + ss;
            uint2 w; w.x = pk2bf(pf[j].x, pf[j].y); w.y = pk2bf(pf[j].z, pf[j].w);
            *(uint2*)(dst + blk * 528 + (r & 31) * 16 + e4 * 8) = w;
        }
    }
    __syncthreads();

    floatx16 acc = {};
    for (int c8 = 0; c8 < 8; ++c8) {
        // prefetch next chunk into regs (independent; scheduler hoists)
        if (c8 < 7) {
            const float* xp = xrow + (c8 + 1) * 256;
            #pragma unroll
            for (int j = 0; j < 16; ++j) pf[j] = *(const float4*)(xp + j * 16);
        }
        // compute on buf[c8&1]
        const unsigned char* bb = lds + (c8 & 1) * K1_BUF;
        const unsigned short* ab = WcombT + (((long)(c8 * 2 + m) * 16) * 2) * 32 * 8;
        #pragma unroll
        for (int ks = 0; ks < 16; ++ks) {
            short8 af = *(const short8*)(ab + ((ks * 2 + s) * 32 + l31) * 8);
            short8 bf = *(const short8*)(bb + ((th * 16 + ks) * 2 + s) * 528 + l31 * 16);
            acc = MFMA32(af, bf, acc);
        }
        // stage next chunk
        if (c8 < 7) {
            unsigned char* dst = lds + ((c8 + 1) & 1) * K1_BUF;
            #pragma unroll
            for (int j = 0; j < 16; ++j) {
                int mm = c4 + 4 * j;
                int ks = mm >> 2, ss = (mm >> 1) & 1, e4 = mm & 1;
                int blk = ((r >> 5) * 16 + ks) * 2 + ss;
                uint2 w; w.x = pk2bf(pf[j].x, pf[j].y); w.y = pk2bf(pf[j].z, pf[j].w);
                *(uint2*)(dst + blk * 528 + (r & 31) * 16 + e4 * 8) = w;
            }
        }
        __syncthreads();
    }
    // ---- epilogue: C -> LDS transpose -> bias/elu -> coalesced S store ----
    float* Cbuf = (float*)lds;          // 64 x 65 fp32 = 16,640 B (buffers dead)
    #pragma unroll
    for (int reg = 0; reg < 16; ++reg) {
        int r0 = (reg & 3) + 8 * (reg >> 2) + 4 * s;
        Cbuf[(m * 32 + r0) * 65 + th * 32 + l31] = acc[reg];
    }
    __syncthreads();
    int mr = tid & 63, tg = tid >> 6;
    float bias = (mr < 32) ? wg_bs[mr] : wg_b1[mr - 32];
    #pragma unroll
    for (int g = 0; g < 16; ++g) {
        int t = tg * 16 + g;
        float v = Cbuf[mr * 65 + t] + bias;
        if (mr >= 32) v = elu1(v);
        S[(tok0 + t) * 64 + mr] = v;
    }
}

// ============================================================================
// K2: per-token z = h1e@Wc2 + bc2 (folded) ; w = softmax(LN(skip+glu(z)))
// ============================================================================
__launch_bounds__(256, 4)
__global__ void k2_token(const float* __restrict__ S,
                         const float* __restrict__ Wc2, const float* __restrict__ bc2,
                         const float* __restrict__ wg_gamma, const float* __restrict__ wg_beta,
                         float* __restrict__ wout) {
    int tid = threadIdx.x;
    int wv = tid >> 6, lane = tid & 63;
    int l31 = lane & 31;
    long t = (long)blockIdx.x * 4 + wv;
    float sv = S[t * 64 + lane];
    float z = bc2[lane];
    #pragma unroll
    for (int k = 0; k < 32; ++k) {
        float hk = __shfl(sv, 32 + k);
        z += hk * Wc2[k * 64 + lane];
    }
    float za   = __shfl(z, l31);
    float zg   = __shfl(z, l31 + 32);
    float skip = __shfl(sv, l31);
    float y = skip + za / (1.f + __expf(-zg));
    float s1 = y;
    #pragma unroll
    for (int mm = 1; mm <= 16; mm <<= 1) s1 += __shfl_xor(s1, mm);
    float mean = s1 * (1.f / 32.f);
    float d = y - mean;
    float s2 = d * d;
    #pragma unroll
    for (int mm = 1; mm <= 16; mm <<= 1) s2 += __shfl_xor(s2, mm);
    float rinv  = rsqrtf(s2 * (1.f / 32.f) + 1e-5f);
    float logit = d * rinv * wg_gamma[l31] + wg_beta[l31];
    float mx = logit;
    #pragma unroll
    for (int mm = 1; mm <= 16; mm <<= 1) mx = fmaxf(mx, __shfl_xor(mx, mm));
    float e = __expf(logit - mx);
    float se = e;
    #pragma unroll
    for (int mm = 1; mm <= 16; mm <<= 1) se += __shfl_xor(se, mm);
    if (lane < 32) wout[t * 32 + lane] = e / se;
}

// ============================================================================
// K3: per-variable GRNs + weighted combine.  A-frags straight from L2 (frag-
// order wAv, identical addrs across waves -> L1). x tile double-buffered in
// frag-order LDS with register prefetch (HBM latency hidden under compute).
// Block = 128 tokens x 8 vars; grid = 256 token-blocks x 4 vgroups.
// ============================================================================
#define K3_BUF 16896      // 32 blks * 528 B
static __device__ __forceinline__ void tile_to_bfrags(const float* t16, int sh,
                                                      short8* f0, short8* f1) {
    unsigned P[8];
    #pragma unroll
    for (int i = 0; i < 8; ++i) P[i] = pk2bf(t16[2 * i], t16[2 * i + 1]);
    unsigned X[8];
    #pragma unroll
    for (int i = 0; i < 8; ++i) X[i] = (unsigned)__shfl_xor((int)P[i], 32);
    union { unsigned u[4]; short8 s8; } a, b;
    a.u[0] = sh ? X[2] : P[0];  a.u[1] = sh ? X[3] : P[1];
    a.u[2] = sh ? P[2] : X[0];  a.u[3] = sh ? P[3] : X[1];
    b.u[0] = sh ? X[6] : P[4];  b.u[1] = sh ? X[7] : P[5];
    b.u[2] = sh ? P[6] : X[4];  b.u[3] = sh ? P[7] : X[5];
    *f0 = a.s8; *f1 = b.s8;
}

__launch_bounds__(256, 3)
__global__ void k3_vgrn(const float* __restrict__ x, const unsigned short* __restrict__ wAv,
                        const float* __restrict__ v_gamma, const float* __restrict__ v_beta,
                        const float* __restrict__ wbuf, float* __restrict__ out) {
    __shared__ __align__(16) unsigned char xls[2 * K3_BUF];
    __shared__ float gb[2][128];
    int tid  = threadIdx.x;
    int wv   = tid >> 6, lane = tid & 63;
    int l31  = lane & 31, s = lane >> 5;
    int vg   = blockIdx.x & 3;
    int tb   = blockIdx.x >> 2;
    int tl   = wv * 32 + l31;
    long tokg = (long)tb * 128 + tl;

    float outacc[32];
    #pragma unroll
    for (int i = 0; i < 32; ++i) outacc[i] = 0.f;

    union { unsigned u[4]; short8 s8; } onef;
    onef.u[0] = (s == 0) ? 0x00003F80u : 0u;
    onef.u[1] = 0; onef.u[2] = 0; onef.u[3] = 0;

    // per-v softmax weights for this lane's token (8 consecutive floats)
    union { float4 q[2]; float f[8]; } wv8;
    wv8.q[0] = *(const float4*)(wbuf + tokg * 32 + vg * 8);
    wv8.q[1] = *(const float4*)(wbuf + tokg * 32 + vg * 8 + 4);

    int r   = tid >> 1;          // staging row 0..127
    int hf  = tid & 1;           // row half (128 B)
    const float* xrbase = x + ((long)tb * 128 + r) * VI + vg * 8 * 64 + hf * 32;

    float4 pf[8];
    // ---- prologue: stage v0 + gb[0] ----
    #pragma unroll
    for (int q = 0; q < 8; ++q) pf[q] = *(const float4*)(xrbase + q * 4);
    {
        unsigned char* dst = xls;
        #pragma unroll
        for (int q = 0; q < 4; ++q) {
            int ks = 2 * hf + (q >> 1), ss = q & 1;
            int blk = ((r >> 5) * 4 + ks) * 2 + ss;
            uint4 w;
            w.x = pk2bf(pf[2*q].x,   pf[2*q].y);   w.y = pk2bf(pf[2*q].z,   pf[2*q].w);
            w.z = pk2bf(pf[2*q+1].x, pf[2*q+1].y); w.w = pk2bf(pf[2*q+1].z, pf[2*q+1].w);
            *(uint4*)(dst + blk * 528 + (r & 31) * 16) = w;
        }
    }
    if (tid < 128) {
        int h = tid >> 1;
        gb[0][tid] = (tid & 1) ? v_beta[(vg * 8) * 64 + h] : v_gamma[(vg * 8) * 64 + h];
    }
    __syncthreads();

    for (int j8 = 0; j8 < 8; ++j8) {
        int v = vg * 8 + j8;
        const unsigned char* xb_base = xls + (j8 & 1) * K3_BUF;
        // ---- x B-frags ----
        union { short8 s8; unsigned u[4]; } xb[4];
        #pragma unroll
        for (int ks = 0; ks < 4; ++ks)
            xb[ks].s8 = *(const short8*)(xb_base + ((wv * 4 + ks) * 2 + s) * 528 + l31 * 16);

        // ---- prefetch next v (independent; scheduler hoists under compute) ----
        if (j8 < 7) {
            const float* xp = xrbase + (j8 + 1) * 64;
            #pragma unroll
            for (int q = 0; q < 8; ++q) pf[q] = *(const float4*)(xp + q * 4);
        }

        const unsigned short* wvb = wAv + (long)v * 15360;
        // ---- H1T = W1a @ [XT;1] ----
        floatx16 h1a0 = {}, h1a1 = {};
        #pragma unroll
        for (int ks = 0; ks < 5; ++ks) {
            short8 b = (ks < 4) ? xb[ks].s8 : onef.s8;
            h1a0 = MFMA32(*(const short8*)(wvb + ((0 * 5 + ks) * 2 + s) * 256 + l31 * 8), b, h1a0);
            h1a1 = MFMA32(*(const short8*)(wvb + ((1 * 5 + ks) * 2 + s) * 256 + l31 * 8), b, h1a1);
        }
        short8 h1b[4];
        {
            float t16[16];
            #pragma unroll
            for (int rr = 0; rr < 16; ++rr) t16[rr] = elu1(h1a0[rr]);
            tile_to_bfrags(t16, s, &h1b[0], &h1b[1]);
            #pragma unroll
            for (int rr = 0; rr < 16; ++rr) t16[rr] = elu1(h1a1[rr]);
            tile_to_bfrags(t16, s, &h1b[2], &h1b[3]);
        }
        // ---- GT = Wca @ [H1T;1] (folded; rows 0..63 = a, 64..127 = gate) ----
        floatx16 g0 = {}, g1 = {}, g2 = {}, g3 = {};
        #pragma unroll
        for (int ks = 0; ks < 5; ++ks) {
            short8 b = (ks < 4) ? h1b[ks] : onef.s8;
            g0 = MFMA32(*(const short8*)(wvb + ((2 * 5 + ks) * 2 + s) * 256 + l31 * 8), b, g0);
            g1 = MFMA32(*(const short8*)(wvb + ((3 * 5 + ks) * 2 + s) * 256 + l31 * 8), b, g1);
            g2 = MFMA32(*(const short8*)(wvb + ((4 * 5 + ks) * 2 + s) * 256 + l31 * 8), b, g2);
            g3 = MFMA32(*(const short8*)(wvb + ((5 * 5 + ks) * 2 + s) * 256 + l31 * 8), b, g3);
        }
        // ---- skip extraction from xb frags (half-swap via shfl_xor 32) ----
        unsigned ownu[4][2], Xu[4][2];
        #pragma unroll
        for (int kk = 0; kk < 4; ++kk) {
            #pragma unroll
            for (int d = 0; d < 2; ++d) {
                ownu[kk][d] = s ? xb[kk].u[2 + d] : xb[kk].u[d];
                unsigned R  = s ? xb[kk].u[d]     : xb[kk].u[2 + d];
                Xu[kk][d]   = (unsigned)__shfl_xor((int)R, 32);
            }
        }
        // ---- glu + skip + LN + weighted combine ----
        float y[32];
        #pragma unroll
        for (int rr = 0; rr < 16; ++rr) {
            int a = rr >> 2, b_ = rr & 3, d = b_ >> 1, kk = a >> 1;
            bool odd = (a & 1);
            unsigned v0 = odd ? (s ? ownu[kk][d]     : Xu[kk][d])
                              : (s ? Xu[kk][d]       : ownu[kk][d]);
            unsigned v1 = odd ? (s ? ownu[2+kk][d]   : Xu[2+kk][d])
                              : (s ? Xu[2+kk][d]     : ownu[2+kk][d]);
            float sk0 = (b_ & 1) ? bfhi(v0) : bflo(v0);
            float sk1 = (b_ & 1) ? bfhi(v1) : bflo(v1);
            y[rr]      = sk0 + g0[rr] / (1.f + __expf(-g2[rr]));
            y[16 + rr] = sk1 + g1[rr] / (1.f + __expf(-g3[rr]));
        }
        float s1 = 0.f;
        #pragma unroll
        for (int i = 0; i < 32; ++i) s1 += y[i];
        s1 += __shfl_xor(s1, 32);
        float mean = s1 * (1.f / 64.f);
        float s2 = 0.f;
        #pragma unroll
        for (int i = 0; i < 32; ++i) { float d = y[i] - mean; s2 += d * d; }
        s2 += __shfl_xor(s2, 32);
        float rinv = rsqrtf(s2 * (1.f / 64.f) + 1e-5f);
        float wvv = wv8.f[j8];
        #pragma unroll
        for (int rr = 0; rr < 16; ++rr) {
            int hr = (rr & 3) + 8 * (rr >> 2) + 4 * s;
            float pv0 = (y[rr]      - mean) * rinv * gb[j8 & 1][2*hr]        + gb[j8 & 1][2*hr + 1];
            float pv1 = (y[16 + rr] - mean) * rinv * gb[j8 & 1][2*(hr+32)]   + gb[j8 & 1][2*(hr+32) + 1];
            outacc[rr]      += wvv * pv0;
            outacc[16 + rr] += wvv * pv1;
        }
        // ---- stage next v into other buffer ----
        if (j8 < 7) {
            unsigned char* dst = xls + ((j8 + 1) & 1) * K3_BUF;
            #pragma unroll
            for (int q = 0; q < 4; ++q) {
                int ks = 2 * hf + (q >> 1), ss = q & 1;
                int blk = ((r >> 5) * 4 + ks) * 2 + ss;
                uint4 w;
                w.x = pk2bf(pf[2*q].x,   pf[2*q].y);   w.y = pk2bf(pf[2*q].z,   pf[2*q].w);
                w.z = pk2bf(pf[2*q+1].x, pf[2*q+1].y); w.w = pk2bf(pf[2*q+1].z, pf[2*q+1].w);
                *(uint4*)(dst + blk * 528 + (r & 31) * 16) = w;
            }
            if (tid < 128) {
                int h = tid >> 1;
                gb[(j8 + 1) & 1][tid] = (tid & 1) ? v_beta[(v + 1) * 64 + h]
                                                  : v_gamma[(v + 1) * 64 + h];
            }
            __syncthreads();
        }
    }
    // ---- combine across 4 vgroups via atomics ----
    #pragma unroll
    for (int rr = 0; rr < 16; ++rr) {
        int hr = (rr & 3) + 8 * (rr >> 2) + 4 * s;
        atomicAdd(out + tokg * 64 + hr,      outacc[rr]);
        atomicAdd(out + tokg * 64 + 32 + hr, outacc[16 + rr]);
    }
}

// ============================================================================
extern "C" void kernel_launch(void* const* d_in, const int* in_sizes, int n_in,
                              void* d_out, int out_size, void* d_ws, size_t ws_size,
                              hipStream_t stream) {
    const float* x        = (const float*)d_in[0];
    const float* wg_W1    = (const float*)d_in[1];
    const float* wg_b1    = (const float*)d_in[2];
    const float* wg_W2    = (const float*)d_in[3];
    const float* wg_b2    = (const float*)d_in[4];
    const float* wg_Wg    = (const float*)d_in[5];
    const float* wg_bg    = (const float*)d_in[6];
    const float* wg_Ws    = (const float*)d_in[7];
    const float* wg_bs    = (const float*)d_in[8];
    const float* wg_gamma = (const float*)d_in[9];
    const float* wg_beta  = (const float*)d_in[10];
    const float* v_W1     = (const float*)d_in[11];
    const float* v_b1     = (const float*)d_in[12];
    const float* v_W2     = (const float*)d_in[13];
    const float* v_b2     = (const float*)d_in[14];
    const float* v_Wg     = (const float*)d_in[15];
    const float* v_bg     = (const float*)d_in[16];
    const float* v_gamma  = (const float*)d_in[17];
    const float* v_beta   = (const float*)d_in[18];
    (void)in_sizes; (void)n_in; (void)ws_size;

    char* ws = (char*)d_ws;
    float* S               = (float*)(ws + WS_S);
    float* wbuf            = (float*)(ws + WS_WBUF);
    unsigned short* WcombT = (unsigned short*)(ws + WS_WCOMBT);
    unsigned short* wAv    = (unsigned short*)(ws + WS_WAV);
    float* Wc2             = (float*)(ws + WS_WC2);
    float* bc2             = (float*)(ws + WS_BC2);
    float* out             = (float*)d_out;

    hipMemsetAsync(d_out, 0, (size_t)out_size * sizeof(float), stream);
    k0_prep<<<1024, 256, 0, stream>>>(wg_W1, wg_Ws, wg_W2, wg_b2, wg_Wg, wg_bg,
                                      v_W1, v_b1, v_W2, v_b2, v_Wg, v_bg,
                                      WcombT, wAv, Wc2, bc2);
    k1_wgemm<<<512, 256, 0, stream>>>(x, WcombT, wg_bs, wg_b1, S);
    k2_token<<<8192, 256, 0, stream>>>(S, Wc2, bc2, wg_gamma, wg_beta, wbuf);
    k3_vgrn<<<1024, 256, 0, stream>>>(x, wAv, v_gamma, v_beta, wbuf, out);
}